// Round 7
// baseline (1449.822 us; speedup 1.0000x reference)
//
#include <hip/hip_runtime.h>
#include <math.h>
#include <stddef.h>

#define N_NODES 16384
#define F_DIM   500
#define KP1     512
#define E_DIM   128
#define C_DIM   10
#define B_DIM   4096
#define MAXDEG  128

typedef __attribute__((ext_vector_type(8))) short short8;   // 8 bf16 = 4 VGPRs
typedef __attribute__((ext_vector_type(4))) float f32x4;    // MFMA C/D

__device__ inline unsigned short f2bf(float f) {
    union { float f; unsigned int u; } v; v.f = f;
    unsigned int u = v.u;
    u += 0x7FFFu + ((u >> 16) & 1u);        // RNE
    return (unsigned short)(u >> 16);
}
__device__ inline float bf2f(unsigned short u) {
    union { unsigned int u; float f; } v; v.u = (unsigned int)u << 16;
    return v.f;
}

// ---------------------------------------------------------------------------
// Merged weight prep (block-ranged):
//  [0,512):   Wt1 [256][512] bf16 (W1 rows split at col 500) — GEMM1 B operand
//  [512,528): W2ta[k][e] = W2[e][k]       (fp32 128x128 transpose)
//  [528,544): W2tb[k][e] = W2[e][128+k]   (fp32 128x128 transpose)
//  [544,560): Wl1t[k][e] = Wl1[e][k]      (fp32 128x128 transpose)
// ---------------------------------------------------------------------------
__global__ __launch_bounds__(256) void k_prep(const float* __restrict__ W1,
                                              const float* __restrict__ W2,
                                              const float* __restrict__ Wl1,
                                              unsigned short* __restrict__ Wt1,
                                              float* __restrict__ W2ta,
                                              float* __restrict__ W2tb,
                                              float* __restrict__ Wl1t) {
    const int bb = blockIdx.x;
    const int t = threadIdx.x;
    if (bb < 512) {
        int idx = bb * 256 + t;                   // 256*512
        int n = idx >> 9, k = idx & 511;
        float v = (k < F_DIM) ? W1[(size_t)(n & 127) * 1000 + (n >> 7) * F_DIM + k] : 0.0f;
        Wt1[idx] = f2bf(v);
    } else {
        // fp32 128x128 tiled transpose: dst[k*128+e] = src[e*S + cOff + k]
        const float* src; float* dst; int S, cOff;
        int tb;
        if (bb < 528)      { src = W2;  dst = W2ta; S = 256; cOff = 0;   tb = bb - 512; }
        else if (bb < 544) { src = W2;  dst = W2tb; S = 256; cOff = 128; tb = bb - 528; }
        else               { src = Wl1; dst = Wl1t; S = 128; cOff = 0;   tb = bb - 544; }
        __shared__ float tile[32][33];
        int k0 = (tb & 3) * 32, e0 = (tb >> 2) * 32;
        int tx = t & 31, ty0 = t >> 5;            // ty0 0..7
#pragma unroll
        for (int q = 0; q < 4; ++q) {
            int ty = ty0 + q * 8;
            tile[ty][tx] = src[(size_t)(e0 + ty) * S + cOff + k0 + tx];
        }
        __syncthreads();
#pragma unroll
        for (int q = 0; q < 4; ++q) {
            int ty = ty0 + q * 8;
            dst[(size_t)(k0 + ty) * 128 + e0 + tx] = tile[tx][ty];
        }
    }
}

// ---------------------------------------------------------------------------
// k_mix (block-ranged, independent work co-scheduled):
//  [0,512):      GEMM1: X[32-row tile][256] = data(fp32->bf16) @ Wt1^T, bf16 out
//  [512,16896):  adj-row scan -> CSR (nbr ushort, deg int)
// ---------------------------------------------------------------------------
__global__ __launch_bounds__(256) void k_mix(const float* __restrict__ data,
                                             const unsigned short* __restrict__ Wt1,
                                             unsigned short* __restrict__ Xb16,
                                             const float* __restrict__ adj,
                                             unsigned short* __restrict__ nbr,
                                             int* __restrict__ deg) {
    __shared__ alignas(16) unsigned char s_raw[(32 * 40 + 256 * 40) * 2];
    const int bb = blockIdx.x;
    const int tid = threadIdx.x;

    if (bb < 512) {
        // ---------------- GEMM1 path ----------------
        unsigned short* sA = (unsigned short*)s_raw;          // 32 x 40
        unsigned short* sB = sA + 32 * 40;                    // 256 x 40
        const int w    = tid >> 6;
        const int lane = tid & 63;
        const int l16  = lane & 15;
        const int quad = lane >> 4;
        const int blockM = bb * 32;
        f32x4 acc[2][4] = {};
#pragma unroll 1
        for (int c = 0; c < (KP1 >> 5); ++c) {
            const int k0 = c << 5;
            if (tid < 128) {                  // A tile: 32 rows x 32 (fp32->bf16)
                int row = tid >> 2, cc = tid & 3;
                int kbase = k0 + cc * 8;
                const float* Arow = data + (size_t)(blockM + row) * F_DIM;
                float4 f0 = (kbase + 4 <= F_DIM) ? *(const float4*)(Arow + kbase)
                                                 : make_float4(0.f, 0.f, 0.f, 0.f);
                float4 f1 = (kbase + 8 <= F_DIM) ? *(const float4*)(Arow + kbase + 4)
                                                 : make_float4(0.f, 0.f, 0.f, 0.f);
                short8 v;
                v[0] = (short)f2bf(f0.x); v[1] = (short)f2bf(f0.y);
                v[2] = (short)f2bf(f0.z); v[3] = (short)f2bf(f0.w);
                v[4] = (short)f2bf(f1.x); v[5] = (short)f2bf(f1.y);
                v[6] = (short)f2bf(f1.z); v[7] = (short)f2bf(f1.w);
                *(short8*)(sA + row * 40 + cc * 8) = v;
            }
#pragma unroll
            for (int q = 0; q < 4; ++q) {     // B tile: 256 rows x 32 bf16
                int idx = tid + 256 * q;
                int row = idx >> 2, cc = idx & 3;
                short8 v = *(const short8*)(Wt1 + (size_t)row * KP1 + k0 + cc * 8);
                *(short8*)(sB + row * 40 + cc * 8) = v;
            }
            __syncthreads();
            short8 af[2], bf[4];
#pragma unroll
            for (int mt = 0; mt < 2; ++mt)
                af[mt] = *(const short8*)(sA + (mt * 16 + l16) * 40 + quad * 8);
#pragma unroll
            for (int nt = 0; nt < 4; ++nt)
                bf[nt] = *(const short8*)(sB + (w * 64 + nt * 16 + l16) * 40 + quad * 8);
#pragma unroll
            for (int mt = 0; mt < 2; ++mt)
#pragma unroll
                for (int nt = 0; nt < 4; ++nt)
                    acc[mt][nt] = __builtin_amdgcn_mfma_f32_16x16x32_bf16(af[mt], bf[nt], acc[mt][nt], 0, 0, 0);
            __syncthreads();
        }
        // C/D layout: col = lane&15, row = quad*4 + reg   [verified m89/m91]
#pragma unroll
        for (int mt = 0; mt < 2; ++mt)
#pragma unroll
            for (int nt = 0; nt < 4; ++nt) {
                int col = w * 64 + nt * 16 + l16;
#pragma unroll
                for (int r = 0; r < 4; ++r) {
                    int row = blockM + mt * 16 + quad * 4 + r;
                    Xb16[(size_t)row * 256 + col] = f2bf(acc[mt][nt][r]);
                }
            }
    } else {
        // ---------------- adj scan path ----------------
        const int i = bb - 512;
        int* s_cnt = (int*)s_raw;
        int* s_idx = ((int*)s_raw) + 4;       // offset 16 B
        const float4* row4 = (const float4*)(adj + (size_t)i * N_NODES);
        if (tid == 0) *s_cnt = 0;
        __syncthreads();
        float4 v[16];
#pragma unroll
        for (int p = 0; p < 16; ++p) v[p] = row4[p * 256 + tid];
#pragma unroll
        for (int p = 0; p < 16; ++p) {
            int col = p * 1024 + tid * 4;
            if (v[p].x != 0.f) { int q = atomicAdd(s_cnt, 1); if (q < MAXDEG) s_idx[q] = col;     }
            if (v[p].y != 0.f) { int q = atomicAdd(s_cnt, 1); if (q < MAXDEG) s_idx[q] = col + 1; }
            if (v[p].z != 0.f) { int q = atomicAdd(s_cnt, 1); if (q < MAXDEG) s_idx[q] = col + 2; }
            if (v[p].w != 0.f) { int q = atomicAdd(s_cnt, 1); if (q < MAXDEG) s_idx[q] = col + 3; }
        }
        __syncthreads();
        int cnt = *s_cnt; if (cnt > MAXDEG) cnt = MAXDEG;   // deg>=1 (self-loop)
        if (tid < cnt) nbr[(size_t)i * MAXDEG + tid] = (unsigned short)s_idx[tid];
        if (tid == 0) deg[i] = cnt;
    }
}

// ---------------------------------------------------------------------------
// Layer-1 gather + relu + l2norm: one 256-thr block per node.
// H1b[i] = bf16( l2norm(relu(Xa[i] + mean_j Xb[j] + b1)) )
// Xb16: [i][0:128]=Xa, [i][128:256]=Xb (bf16). 8-way neighbor-parallel;
// each of 8 groups reads ushort4/lane (32 lanes x 8 B = one 256 B row).
// ---------------------------------------------------------------------------
__global__ __launch_bounds__(256) void k_gather(const unsigned short* __restrict__ nbr,
                                                const int* __restrict__ deg,
                                                const unsigned short* __restrict__ Xb16,
                                                const float* __restrict__ b1,
                                                unsigned short* __restrict__ H1b) {
    const int i = blockIdx.x;
    const int t = threadIdx.x;
    const int cnt = deg[i];
    __shared__ int s_idx[MAXDEG];
    __shared__ float s_part[8][128];
    __shared__ float s_w[2];
    if (t < cnt) s_idx[t] = nbr[(size_t)i * MAXDEG + t];
    __syncthreads();
    const int g = t >> 5, l = t & 31;
    float4 a4 = make_float4(0.f, 0.f, 0.f, 0.f);
    for (int k = g; k < cnt; k += 8) {
        ushort4 x4 = ((const ushort4*)(Xb16 + (size_t)s_idx[k] * 256 + 128))[l];
        a4.x += bf2f(x4.x); a4.y += bf2f(x4.y); a4.z += bf2f(x4.z); a4.w += bf2f(x4.w);
    }
    *(float4*)&s_part[g][l * 4] = a4;
    __syncthreads();
    float vv = 0.f;
    if (t < 128) {
        float tot = 0.f;
#pragma unroll
        for (int g2 = 0; g2 < 8; ++g2) tot += s_part[g2][t];
        vv = bf2f(Xb16[(size_t)i * 256 + t]) + tot / (float)cnt + b1[t];
        vv = fmaxf(vv, 0.f);
        float s = vv * vv;
#pragma unroll
        for (int off = 32; off > 0; off >>= 1) s += __shfl_down(s, off, 64);
        if ((t & 63) == 0) s_w[t >> 6] = s;
    }
    __syncthreads();
    if (t < 128) {
        float denom = fmaxf(sqrtf(s_w[0] + s_w[1]), 1e-12f);
        H1b[(size_t)i * 128 + t] = f2bf(vv / denom);
    }
}

// ---------------------------------------------------------------------------
// Layer-2 + head fused, per batch node b (256 threads). Cached CSR (ushort).
// Mean-linearity: x2 = H1[n]@W2a^T + mean_j(H1[j])@W2b^T + b2 — gathers H1b
// (bf16, 256 B/nbr) and does two fp32 128x128 matvecs in-block. No GEMM2/Y.
// ---------------------------------------------------------------------------
__global__ __launch_bounds__(256) void k_l2head(const int* __restrict__ nodes,
                                                const unsigned short* __restrict__ nbr,
                                                const int* __restrict__ deg,
                                                const unsigned short* __restrict__ H1b,
                                                const float* __restrict__ W2ta,
                                                const float* __restrict__ W2tb,
                                                const float* __restrict__ b2,
                                                const float* __restrict__ Wl1t,
                                                const float* __restrict__ bl1,
                                                const float* __restrict__ Wl2,
                                                const float* __restrict__ bl2,
                                                float* __restrict__ out) {
    const int b = blockIdx.x;
    const int t = threadIdx.x;
    const int n = nodes[b];
    const int cnt = deg[n];
    __shared__ int s_idx[MAXDEG];
    __shared__ float s_part[8][128];
    __shared__ float s_hn[128];
    __shared__ float s_m[128];
    __shared__ float s_h[128];
    __shared__ float s_x[128];
    __shared__ float s_c[C_DIM];
    __shared__ float s_w[2];
    if (t < cnt) s_idx[t] = nbr[(size_t)n * MAXDEG + t];
    __syncthreads();
    // gather mean of neighbor H1 rows (bf16, 32 lanes x ushort4 = 256 B/row)
    const int g = t >> 5, l = t & 31;
    float4 a4 = make_float4(0.f, 0.f, 0.f, 0.f);
    for (int k = g; k < cnt; k += 8) {
        ushort4 h4 = ((const ushort4*)(H1b + (size_t)s_idx[k] * 128))[l];
        a4.x += bf2f(h4.x); a4.y += bf2f(h4.y); a4.z += bf2f(h4.z); a4.w += bf2f(h4.w);
    }
    *(float4*)&s_part[g][l * 4] = a4;
    __syncthreads();
    if (t < 128) {
        float tot = 0.f;
#pragma unroll
        for (int g2 = 0; g2 < 8; ++g2) tot += s_part[g2][t];
        s_m[t]  = tot / (float)cnt;
        s_hn[t] = bf2f(H1b[(size_t)n * 128 + t]);
    }
    __syncthreads();
    if (t < 128) {
        // x2[t] = hn . W2ta[:,t] + m . W2tb[:,t] + b2[t]
        float v = b2[t];
#pragma unroll 4
        for (int kk = 0; kk < 128; ++kk)
            v += s_hn[kk] * W2ta[kk * 128 + t] + s_m[kk] * W2tb[kk * 128 + t];
        v = fmaxf(v, 0.f);
        float s = v * v;
#pragma unroll
        for (int off = 32; off > 0; off >>= 1) s += __shfl_down(s, off, 64);
        if ((t & 63) == 0) s_w[t >> 6] = s;
        __syncthreads();
        float denom = fmaxf(sqrtf(s_w[0] + s_w[1]), 1e-12f);
        s_h[t] = v / denom;
    } else {
        __syncthreads();
    }
    __syncthreads();
    if (t < 128) {
        float x1 = bl1[t];
#pragma unroll 8
        for (int kk = 0; kk < 128; ++kk)
            x1 += Wl1t[kk * 128 + t] * s_h[kk];
        s_x[t] = x1;
    }
    __syncthreads();
    if (t < C_DIM) {
        float l2 = bl2[t];
        const float* wr = Wl2 + (size_t)t * 128;
        for (int kk = 0; kk < 128; ++kk) l2 += wr[kk] * s_x[kk];
        s_c[t] = l2;
    }
    __syncthreads();
    if (t < C_DIM) {
        float mx = -1e30f;
        for (int c = 0; c < C_DIM; ++c) mx = fmaxf(mx, s_c[c]);
        float se = 0.f;
        for (int c = 0; c < C_DIM; ++c) se += expf(s_c[c] - mx);
        out[(size_t)b * C_DIM + t] = expf(s_c[t] - mx) / se;
    }
}

// ---------------------------------------------------------------------------
// Launch
// ---------------------------------------------------------------------------
extern "C" void kernel_launch(void* const* d_in, const int* in_sizes, int n_in,
                              void* d_out, int out_size, void* d_ws, size_t ws_size,
                              hipStream_t stream) {
    const int*   nodes = (const int*)  d_in[0];
    const float* adj   = (const float*)d_in[1];
    const float* data  = (const float*)d_in[2];
    const float* W1    = (const float*)d_in[3];
    const float* b1    = (const float*)d_in[4];
    const float* W2    = (const float*)d_in[5];
    const float* b2    = (const float*)d_in[6];
    const float* Wl1   = (const float*)d_in[7];
    const float* bl1   = (const float*)d_in[8];
    const float* Wl2   = (const float*)d_in[9];
    const float* bl2   = (const float*)d_in[10];
    float* out = (float*)d_out;

    // workspace layout: fp32 arrays first, then bf16/ushort, then int
    float* W2ta = (float*)d_ws;                             // 128*128
    float* W2tb = W2ta + 16384;                             // 128*128
    float* Wl1t = W2tb + 16384;                             // 128*128
    unsigned short* Wt1  = (unsigned short*)(Wl1t + 16384); // 256*512
    unsigned short* Xb16 = Wt1 + 256 * KP1;                 // 16384*256
    unsigned short* H1b  = Xb16 + (size_t)N_NODES * 256;    // 16384*128
    unsigned short* nbr  = H1b + (size_t)N_NODES * 128;     // 16384*128
    int* deg = (int*)(nbr + (size_t)N_NODES * MAXDEG);      // 16384

    // merged weight prep
    k_prep<<<560, 256, 0, stream>>>(W1, W2, Wl1, Wt1, W2ta, W2tb, Wl1t);

    // GEMM1 (bf16 out) + adj scan co-scheduled, then layer-1 gather+norm
    k_mix   <<<512 + N_NODES, 256, 0, stream>>>(data, Wt1, Xb16, adj, nbr, deg);
    k_gather<<<N_NODES, 256, 0, stream>>>(nbr, deg, Xb16, b1, H1b);

    // layer 2 + head fused (mean-linearity, no GEMM2/Y)
    k_l2head<<<B_DIM, 256, 0, stream>>>(nodes, nbr, deg, H1b, W2ta, W2tb, b2,
                                        Wl1t, bl1, Wl2, bl2, out);
}

// Round 8
// 1417.079 us; speedup vs baseline: 1.0231x; 1.0231x over previous
//
#include <hip/hip_runtime.h>
#include <math.h>
#include <stddef.h>

#define N_NODES 16384
#define F_DIM   500
#define KP1     512
#define E_DIM   128
#define C_DIM   10
#define B_DIM   4096
#define MAXDEG  128

typedef __attribute__((ext_vector_type(8))) short short8;   // 8 bf16 = 4 VGPRs
typedef __attribute__((ext_vector_type(4))) float f32x4;    // MFMA C/D

__device__ inline unsigned short f2bf(float f) {
    union { float f; unsigned int u; } v; v.f = f;
    unsigned int u = v.u;
    u += 0x7FFFu + ((u >> 16) & 1u);        // RNE
    return (unsigned short)(u >> 16);
}
__device__ inline float bf2f(unsigned short u) {
    union { unsigned int u; float f; } v; v.u = (unsigned int)u << 16;
    return v.f;
}

// ---------------------------------------------------------------------------
// Merged weight prep (block-ranged):
//  [0,512):   Wt1 [256][512] bf16 (W1 rows split at col 500) — GEMM1 B^T
//  [512,576): W2ab16[n][k] = bf16(W2[n][k])        (B^T for Ya GEMM)
//  [576,640): W2bb16[n][k] = bf16(W2[n][128+k])    (B^T for Yb GEMM)
//  [640,656): Wl1t[k][e] = Wl1[e][k]               (fp32 128x128 transpose)
// ---------------------------------------------------------------------------
__global__ __launch_bounds__(256) void k_prep(const float* __restrict__ W1,
                                              const float* __restrict__ W2,
                                              const float* __restrict__ Wl1,
                                              unsigned short* __restrict__ Wt1,
                                              unsigned short* __restrict__ W2ab16,
                                              unsigned short* __restrict__ W2bb16,
                                              float* __restrict__ Wl1t) {
    const int bb = blockIdx.x;
    const int t = threadIdx.x;
    if (bb < 512) {
        int idx = bb * 256 + t;                   // 256*512
        int n = idx >> 9, k = idx & 511;
        float v = (k < F_DIM) ? W1[(size_t)(n & 127) * 1000 + (n >> 7) * F_DIM + k] : 0.0f;
        Wt1[idx] = f2bf(v);
    } else if (bb < 576) {
        int idx = (bb - 512) * 256 + t;           // 128*128
        int n = idx >> 7, k = idx & 127;
        W2ab16[idx] = f2bf(W2[(size_t)n * 256 + k]);
    } else if (bb < 640) {
        int idx = (bb - 576) * 256 + t;           // 128*128
        int n = idx >> 7, k = idx & 127;
        W2bb16[idx] = f2bf(W2[(size_t)n * 256 + 128 + k]);
    } else {
        __shared__ float tile[32][33];
        int tb = bb - 640;                        // 16 tiles (4x4)
        int k0 = (tb & 3) * 32, e0 = (tb >> 2) * 32;
        int tx = t & 31, ty0 = t >> 5;
#pragma unroll
        for (int q = 0; q < 4; ++q) {
            int ty = ty0 + q * 8;
            tile[ty][tx] = Wl1[(size_t)(e0 + ty) * 128 + k0 + tx];
        }
        __syncthreads();
#pragma unroll
        for (int q = 0; q < 4; ++q) {
            int ty = ty0 + q * 8;
            Wl1t[(size_t)(k0 + ty) * 128 + e0 + tx] = tile[tx][ty];
        }
    }
}

// ---------------------------------------------------------------------------
// k_mix (block-ranged, independent work co-scheduled):
//  [0,512):      GEMM1: Xb16[32-row tile][256] = data(fp32->bf16) @ Wt1^T
//  [512,16896):  adj-row scan -> CSR (nbr ushort, deg int)
// ---------------------------------------------------------------------------
__global__ __launch_bounds__(256) void k_mix(const float* __restrict__ data,
                                             const unsigned short* __restrict__ Wt1,
                                             unsigned short* __restrict__ Xb16,
                                             const float* __restrict__ adj,
                                             unsigned short* __restrict__ nbr,
                                             int* __restrict__ deg) {
    __shared__ alignas(16) unsigned char s_raw[(32 * 40 + 256 * 40) * 2];
    const int bb = blockIdx.x;
    const int tid = threadIdx.x;

    if (bb < 512) {
        // ---------------- GEMM1 path ----------------
        unsigned short* sA = (unsigned short*)s_raw;          // 32 x 40
        unsigned short* sB = sA + 32 * 40;                    // 256 x 40
        const int w    = tid >> 6;
        const int lane = tid & 63;
        const int l16  = lane & 15;
        const int quad = lane >> 4;
        const int blockM = bb * 32;
        f32x4 acc[2][4] = {};
#pragma unroll 1
        for (int c = 0; c < (KP1 >> 5); ++c) {
            const int k0 = c << 5;
            if (tid < 128) {                  // A tile: 32 rows x 32 (fp32->bf16)
                int row = tid >> 2, cc = tid & 3;
                int kbase = k0 + cc * 8;
                const float* Arow = data + (size_t)(blockM + row) * F_DIM;
                float4 f0 = (kbase + 4 <= F_DIM) ? *(const float4*)(Arow + kbase)
                                                 : make_float4(0.f, 0.f, 0.f, 0.f);
                float4 f1 = (kbase + 8 <= F_DIM) ? *(const float4*)(Arow + kbase + 4)
                                                 : make_float4(0.f, 0.f, 0.f, 0.f);
                short8 v;
                v[0] = (short)f2bf(f0.x); v[1] = (short)f2bf(f0.y);
                v[2] = (short)f2bf(f0.z); v[3] = (short)f2bf(f0.w);
                v[4] = (short)f2bf(f1.x); v[5] = (short)f2bf(f1.y);
                v[6] = (short)f2bf(f1.z); v[7] = (short)f2bf(f1.w);
                *(short8*)(sA + row * 40 + cc * 8) = v;
            }
#pragma unroll
            for (int q = 0; q < 4; ++q) {     // B tile: 256 rows x 32 bf16
                int idx = tid + 256 * q;
                int row = idx >> 2, cc = idx & 3;
                short8 v = *(const short8*)(Wt1 + (size_t)row * KP1 + k0 + cc * 8);
                *(short8*)(sB + row * 40 + cc * 8) = v;
            }
            __syncthreads();
            short8 af[2], bf[4];
#pragma unroll
            for (int mt = 0; mt < 2; ++mt)
                af[mt] = *(const short8*)(sA + (mt * 16 + l16) * 40 + quad * 8);
#pragma unroll
            for (int nt = 0; nt < 4; ++nt)
                bf[nt] = *(const short8*)(sB + (w * 64 + nt * 16 + l16) * 40 + quad * 8);
#pragma unroll
            for (int mt = 0; mt < 2; ++mt)
#pragma unroll
                for (int nt = 0; nt < 4; ++nt)
                    acc[mt][nt] = __builtin_amdgcn_mfma_f32_16x16x32_bf16(af[mt], bf[nt], acc[mt][nt], 0, 0, 0);
            __syncthreads();
        }
        // C/D layout: col = lane&15, row = quad*4 + reg   [verified m89/m91]
#pragma unroll
        for (int mt = 0; mt < 2; ++mt)
#pragma unroll
            for (int nt = 0; nt < 4; ++nt) {
                int col = w * 64 + nt * 16 + l16;
#pragma unroll
                for (int r = 0; r < 4; ++r) {
                    int row = blockM + mt * 16 + quad * 4 + r;
                    Xb16[(size_t)row * 256 + col] = f2bf(acc[mt][nt][r]);
                }
            }
    } else {
        // ---------------- adj scan path ----------------
        const int i = bb - 512;
        int* s_cnt = (int*)s_raw;
        int* s_idx = ((int*)s_raw) + 4;       // offset 16 B
        const float4* row4 = (const float4*)(adj + (size_t)i * N_NODES);
        if (tid == 0) *s_cnt = 0;
        __syncthreads();
        float4 v[16];
#pragma unroll
        for (int p = 0; p < 16; ++p) v[p] = row4[p * 256 + tid];
#pragma unroll
        for (int p = 0; p < 16; ++p) {
            int col = p * 1024 + tid * 4;
            if (v[p].x != 0.f) { int q = atomicAdd(s_cnt, 1); if (q < MAXDEG) s_idx[q] = col;     }
            if (v[p].y != 0.f) { int q = atomicAdd(s_cnt, 1); if (q < MAXDEG) s_idx[q] = col + 1; }
            if (v[p].z != 0.f) { int q = atomicAdd(s_cnt, 1); if (q < MAXDEG) s_idx[q] = col + 2; }
            if (v[p].w != 0.f) { int q = atomicAdd(s_cnt, 1); if (q < MAXDEG) s_idx[q] = col + 3; }
        }
        __syncthreads();
        int cnt = *s_cnt; if (cnt > MAXDEG) cnt = MAXDEG;   // deg>=1 (self-loop)
        if (tid < cnt) nbr[(size_t)i * MAXDEG + tid] = (unsigned short)s_idx[tid];
        if (tid == 0) deg[i] = cnt;
    }
}

// ---------------------------------------------------------------------------
// Layer-1 gather + relu + l2norm: one 256-thr block per node.
// H1b[i] = bf16( l2norm(relu(Xa[i] + mean_j Xb[j] + b1)) )
// Xb16: [i][0:128]=Xa, [i][128:256]=Xb (bf16). 8-way neighbor-parallel.
// ---------------------------------------------------------------------------
__global__ __launch_bounds__(256) void k_gather(const unsigned short* __restrict__ nbr,
                                                const int* __restrict__ deg,
                                                const unsigned short* __restrict__ Xb16,
                                                const float* __restrict__ b1,
                                                unsigned short* __restrict__ H1b) {
    const int i = blockIdx.x;
    const int t = threadIdx.x;
    const int cnt = deg[i];
    __shared__ int s_idx[MAXDEG];
    __shared__ float s_part[8][128];
    __shared__ float s_w[2];
    if (t < cnt) s_idx[t] = nbr[(size_t)i * MAXDEG + t];
    __syncthreads();
    const int g = t >> 5, l = t & 31;
    float4 a4 = make_float4(0.f, 0.f, 0.f, 0.f);
    for (int k = g; k < cnt; k += 8) {
        ushort4 x4 = ((const ushort4*)(Xb16 + (size_t)s_idx[k] * 256 + 128))[l];
        a4.x += bf2f(x4.x); a4.y += bf2f(x4.y); a4.z += bf2f(x4.z); a4.w += bf2f(x4.w);
    }
    *(float4*)&s_part[g][l * 4] = a4;
    __syncthreads();
    float vv = 0.f;
    if (t < 128) {
        float tot = 0.f;
#pragma unroll
        for (int g2 = 0; g2 < 8; ++g2) tot += s_part[g2][t];
        vv = bf2f(Xb16[(size_t)i * 256 + t]) + tot / (float)cnt + b1[t];
        vv = fmaxf(vv, 0.f);
        float s = vv * vv;
#pragma unroll
        for (int off = 32; off > 0; off >>= 1) s += __shfl_down(s, off, 64);
        if ((t & 63) == 0) s_w[t >> 6] = s;
    }
    __syncthreads();
    if (t < 128) {
        float denom = fmaxf(sqrtf(s_w[0] + s_w[1]), 1e-12f);
        H1b[(size_t)i * 128 + t] = f2bf(vv / denom);
    }
}

// ---------------------------------------------------------------------------
// GEMM2 (block-ranged, both paths K=128, 128 output cols, 32-row tiles):
//  [0,512):   Yb16[i][e] = bf16( H1b[i] @ W2bb16^T )      for all nodes
//  [512,640): Ya[b][e]   =       H1b[nodes[b]] @ W2ab16^T  for batch rows
// Wave w covers cols w*32..w*32+31 (2 m-tiles x 2 n-tiles of 16x16).
// ---------------------------------------------------------------------------
__global__ __launch_bounds__(256) void k_gemm2(const unsigned short* __restrict__ H1b,
                                               const unsigned short* __restrict__ W2bb16,
                                               const unsigned short* __restrict__ W2ab16,
                                               const int* __restrict__ nodes,
                                               unsigned short* __restrict__ Yb16,
                                               float* __restrict__ Ya) {
    __shared__ unsigned short sA[32 * 40];
    __shared__ unsigned short sB[128 * 40];
    const int bb = blockIdx.x;
    const bool selfp = (bb >= 512);
    const unsigned short* B = selfp ? W2ab16 : W2bb16;
    const int blockM = (selfp ? (bb - 512) : bb) * 32;
    const int tid  = threadIdx.x;
    const int w    = tid >> 6;
    const int lane = tid & 63;
    const int l16  = lane & 15;
    const int quad = lane >> 4;
    f32x4 acc[2][2] = {};
#pragma unroll
    for (int c = 0; c < 4; ++c) {          // K = 128
        const int k0 = c << 5;
        if (tid < 128) {                   // A tile: 32 rows x 32 bf16
            int row = tid >> 2, cc = tid & 3;
            int m = blockM + row;
            int src = selfp ? nodes[m] : m;
            short8 v = *(const short8*)(H1b + (size_t)src * 128 + k0 + cc * 8);
            *(short8*)(sA + row * 40 + cc * 8) = v;
        }
#pragma unroll
        for (int q = 0; q < 2; ++q) {      // B tile: 128 rows x 32 bf16
            int idx = tid + 256 * q;
            int row = idx >> 2, cc = idx & 3;
            short8 v = *(const short8*)(B + (size_t)row * 128 + k0 + cc * 8);
            *(short8*)(sB + row * 40 + cc * 8) = v;
        }
        __syncthreads();
        short8 af[2], bf[2];
#pragma unroll
        for (int mt = 0; mt < 2; ++mt)
            af[mt] = *(const short8*)(sA + (mt * 16 + l16) * 40 + quad * 8);
#pragma unroll
        for (int nt = 0; nt < 2; ++nt)
            bf[nt] = *(const short8*)(sB + (w * 32 + nt * 16 + l16) * 40 + quad * 8);
#pragma unroll
        for (int mt = 0; mt < 2; ++mt)
#pragma unroll
            for (int nt = 0; nt < 2; ++nt)
                acc[mt][nt] = __builtin_amdgcn_mfma_f32_16x16x32_bf16(af[mt], bf[nt], acc[mt][nt], 0, 0, 0);
        __syncthreads();
    }
#pragma unroll
    for (int mt = 0; mt < 2; ++mt)
#pragma unroll
        for (int nt = 0; nt < 2; ++nt) {
            int col = w * 32 + nt * 16 + l16;
#pragma unroll
            for (int r = 0; r < 4; ++r) {
                int row = blockM + mt * 16 + quad * 4 + r;
                if (selfp) Ya[(size_t)row * 128 + col] = acc[mt][nt][r];
                else       Yb16[(size_t)row * 128 + col] = f2bf(acc[mt][nt][r]);
            }
        }
}

// ---------------------------------------------------------------------------
// Layer-2 + head fused, per batch node b (256 threads). Cached CSR (ushort).
// vv = Ya[b] + mean_j Yb16[j] + b2 ; H2 = l2norm(relu(vv)); Wl1/Wl2+softmax.
// ---------------------------------------------------------------------------
__global__ __launch_bounds__(256) void k_l2head(const int* __restrict__ nodes,
                                                const unsigned short* __restrict__ nbr,
                                                const int* __restrict__ deg,
                                                const unsigned short* __restrict__ Yb16,
                                                const float* __restrict__ Ya,
                                                const float* __restrict__ b2,
                                                const float* __restrict__ Wl1t,
                                                const float* __restrict__ bl1,
                                                const float* __restrict__ Wl2,
                                                const float* __restrict__ bl2,
                                                float* __restrict__ out) {
    const int b = blockIdx.x;
    const int t = threadIdx.x;
    const int n = nodes[b];
    const int cnt = deg[n];
    __shared__ int s_idx[MAXDEG];
    __shared__ float s_part[8][128];
    __shared__ float s_h[128];
    __shared__ float s_x[128];
    __shared__ float s_c[C_DIM];
    __shared__ float s_w[2];
    if (t < cnt) s_idx[t] = nbr[(size_t)n * MAXDEG + t];
    __syncthreads();
    const int g = t >> 5, l = t & 31;
    float4 a4 = make_float4(0.f, 0.f, 0.f, 0.f);
    for (int k = g; k < cnt; k += 8) {
        ushort4 y4 = ((const ushort4*)(Yb16 + (size_t)s_idx[k] * 128))[l];
        a4.x += bf2f(y4.x); a4.y += bf2f(y4.y); a4.z += bf2f(y4.z); a4.w += bf2f(y4.w);
    }
    *(float4*)&s_part[g][l * 4] = a4;
    __syncthreads();
    float vv = 0.f;
    if (t < 128) {
        float tot = 0.f;
#pragma unroll
        for (int g2 = 0; g2 < 8; ++g2) tot += s_part[g2][t];
        vv = Ya[(size_t)b * 128 + t] + tot / (float)cnt + b2[t];
        vv = fmaxf(vv, 0.f);
        float s = vv * vv;
#pragma unroll
        for (int off = 32; off > 0; off >>= 1) s += __shfl_down(s, off, 64);
        if ((t & 63) == 0) s_w[t >> 6] = s;
    }
    __syncthreads();
    if (t < 128) {
        float denom = fmaxf(sqrtf(s_w[0] + s_w[1]), 1e-12f);
        s_h[t] = vv / denom;
    }
    __syncthreads();
    if (t < 128) {
        float x1 = bl1[t];
#pragma unroll 8
        for (int kk = 0; kk < 128; ++kk)
            x1 += Wl1t[kk * 128 + t] * s_h[kk];
        s_x[t] = x1;
    }
    __syncthreads();
    if (t < C_DIM) {
        float l2 = bl2[t];
        const float* wr = Wl2 + (size_t)t * 128;
        for (int kk = 0; kk < 128; ++kk) l2 += wr[kk] * s_x[kk];
        s_c[t] = l2;
    }
    __syncthreads();
    if (t < C_DIM) {
        float mx = -1e30f;
        for (int c = 0; c < C_DIM; ++c) mx = fmaxf(mx, s_c[c]);
        float se = 0.f;
        for (int c = 0; c < C_DIM; ++c) se += expf(s_c[c] - mx);
        out[(size_t)b * C_DIM + t] = expf(s_c[t] - mx) / se;
    }
}

// ---------------------------------------------------------------------------
// Launch
// ---------------------------------------------------------------------------
extern "C" void kernel_launch(void* const* d_in, const int* in_sizes, int n_in,
                              void* d_out, int out_size, void* d_ws, size_t ws_size,
                              hipStream_t stream) {
    const int*   nodes = (const int*)  d_in[0];
    const float* adj   = (const float*)d_in[1];
    const float* data  = (const float*)d_in[2];
    const float* W1    = (const float*)d_in[3];
    const float* b1    = (const float*)d_in[4];
    const float* W2    = (const float*)d_in[5];
    const float* b2    = (const float*)d_in[6];
    const float* Wl1   = (const float*)d_in[7];
    const float* bl1   = (const float*)d_in[8];
    const float* Wl2   = (const float*)d_in[9];
    const float* bl2   = (const float*)d_in[10];
    float* out = (float*)d_out;

    // workspace layout: fp32 first, then bf16/ushort, then int (16B aligned)
    float* Wl1t = (float*)d_ws;                             // 128*128
    float* Ya   = Wl1t + 16384;                             // 4096*128
    unsigned short* Wt1    = (unsigned short*)(Ya + (size_t)B_DIM * 128); // 256*512
    unsigned short* W2ab16 = Wt1 + 256 * KP1;               // 128*128
    unsigned short* W2bb16 = W2ab16 + 16384;                // 128*128
    unsigned short* Xb16   = W2bb16 + 16384;                // 16384*256
    unsigned short* H1b    = Xb16 + (size_t)N_NODES * 256;  // 16384*128
    unsigned short* Yb16   = H1b + (size_t)N_NODES * 128;   // 16384*128
    unsigned short* nbr    = Yb16 + (size_t)N_NODES * 128;  // 16384*128
    int* deg = (int*)(nbr + (size_t)N_NODES * MAXDEG);      // 16384

    // merged weight prep
    k_prep<<<656, 256, 0, stream>>>(W1, W2, Wl1, Wt1, W2ab16, W2bb16, Wl1t);

    // GEMM1 (bf16 out) + adj scan co-scheduled, then layer-1 gather+norm
    k_mix   <<<512 + N_NODES, 256, 0, stream>>>(data, Wt1, Xb16, adj, nbr, deg);
    k_gather<<<N_NODES, 256, 0, stream>>>(nbr, deg, Xb16, b1, H1b);

    // layer 2: Yb for all nodes + Ya for batch rows (one block-ranged launch)
    k_gemm2 <<<512 + 128, 256, 0, stream>>>(H1b, W2bb16, W2ab16, nodes, Yb16, Ya);

    // fused layer-2 epilogue + classifier head + softmax
    k_l2head<<<B_DIM, 256, 0, stream>>>(nodes, nbr, deg, Yb16, Ya, b2,
                                        Wl1t, bl1, Wl2, bl2, out);
}